// Round 8
// baseline (61.137 us; speedup 1.0000x reference)
//
#include <hip/hip_runtime.h>
#include <hip/hip_bf16.h>

// B=2, N=512, C=256
// score[b,i,j] = sum_c relu(q_ic + k_jc) = 0.5*(Qs_i + Ks_j + sum_c |q_ic + k_jc|)
// Qs_i is row-constant -> cancels in softmax. Kernel uses score' = 0.5*(Sabs_ij + Ks_j).

#define QSTR 132   // q/k LDS stride (dwords)
#define VSTR 260   // v LDS stride (dwords)

// ---------------- Kernel 1: fused QKV projection (LDS double-buffered) ----------------
__global__ __launch_bounds__(256, 2) void gemm_qkv(
    const float* __restrict__ x,
    const float* __restrict__ Wq, const float* __restrict__ Wk, const float* __restrict__ Wv,
    float4* __restrict__ qt4, float* __restrict__ k, float* __restrict__ v,
    float* __restrict__ Ksp)
{
    const int z = blockIdx.z;
    const float* W = (z == 0) ? Wq : ((z == 1) ? Wk : Wv);
    const int row0 = blockIdx.x * 32;
    const int d0   = blockIdx.y * 64;

    __shared__ __attribute__((aligned(16))) float AT[2][32][36];  // [buf][c][row]
    __shared__ __attribute__((aligned(16))) float WT[2][32][68];  // [buf][c][d]

    const int tid = threadIdx.x;
    const int ty = tid >> 4, tx = tid & 15;
    const int ar = tid >> 3, ac = (tid & 7) * 4;   // A staging role
    const int wd = tid >> 2, wc = (tid & 3) * 8;   // W staging role

    const float* xg = x + (size_t)(row0 + ar) * 256 + ac;
    const float* wg = W + (size_t)(d0 + wd) * 256 + wc;

    float4 ra  = *(const float4*)xg;
    float4 rw0 = *(const float4*)wg;
    float4 rw1 = *(const float4*)(wg + 4);

    AT[0][ac+0][ar]=ra.x;  AT[0][ac+1][ar]=ra.y;  AT[0][ac+2][ar]=ra.z;  AT[0][ac+3][ar]=ra.w;
    WT[0][wc+0][wd]=rw0.x; WT[0][wc+1][wd]=rw0.y; WT[0][wc+2][wd]=rw0.z; WT[0][wc+3][wd]=rw0.w;
    WT[0][wc+4][wd]=rw1.x; WT[0][wc+5][wd]=rw1.y; WT[0][wc+6][wd]=rw1.z; WT[0][wc+7][wd]=rw1.w;
    __syncthreads();

    float acc[2][4] = {};

#pragma unroll 1
    for (int kc = 0; kc < 8; ++kc) {
        const int cur = kc & 1;
        if (kc < 7) {   // prefetch next K-chunk into registers (latency hidden by compute)
            ra  = *(const float4*)(xg + (kc + 1) * 32);
            rw0 = *(const float4*)(wg + (kc + 1) * 32);
            rw1 = *(const float4*)(wg + (kc + 1) * 32 + 4);
        }
#pragma unroll
        for (int c = 0; c < 32; ++c) {
            float2 a  = *(const float2*)&AT[cur][c][ty * 2];
            float4 w4 = *(const float4*)&WT[cur][c][tx * 4];
            acc[0][0] += a.x * w4.x; acc[0][1] += a.x * w4.y;
            acc[0][2] += a.x * w4.z; acc[0][3] += a.x * w4.w;
            acc[1][0] += a.y * w4.x; acc[1][1] += a.y * w4.y;
            acc[1][2] += a.y * w4.z; acc[1][3] += a.y * w4.w;
        }
        if (kc < 7) {
            const int nx = cur ^ 1;
            AT[nx][ac+0][ar]=ra.x;  AT[nx][ac+1][ar]=ra.y;  AT[nx][ac+2][ar]=ra.z;  AT[nx][ac+3][ar]=ra.w;
            WT[nx][wc+0][wd]=rw0.x; WT[nx][wc+1][wd]=rw0.y; WT[nx][wc+2][wd]=rw0.z; WT[nx][wc+3][wd]=rw0.w;
            WT[nx][wc+4][wd]=rw1.x; WT[nx][wc+5][wd]=rw1.y; WT[nx][wc+6][wd]=rw1.z; WT[nx][wc+7][wd]=rw1.w;
            __syncthreads();
        }
    }

    if (z == 0) {
#pragma unroll
        for (int rr = 0; rr < 2; ++rr)
            qt4[(size_t)(d0 / 4 + tx) * 1024 + row0 + ty * 2 + rr] =
                make_float4(acc[rr][0], acc[rr][1], acc[rr][2], acc[rr][3]);
    } else {
        float* out = (z == 1) ? k : v;
#pragma unroll
        for (int rr = 0; rr < 2; ++rr)
            *(float4*)&out[(size_t)(row0 + ty * 2 + rr) * 256 + d0 + tx * 4] =
                make_float4(acc[rr][0], acc[rr][1], acc[rr][2], acc[rr][3]);
        if (z == 1) {
#pragma unroll
            for (int rr = 0; rr < 2; ++rr) {
                float kp = acc[rr][0] + acc[rr][1] + acc[rr][2] + acc[rr][3];
#pragma unroll
                for (int d = 1; d < 16; d <<= 1) kp += __shfl_xor(kp, d, 16);
                if (tx == 0)
                    Ksp[(size_t)(d0 >> 6) * 1024 + row0 + ty * 2 + rr] = kp;
            }
        }
    }
}

// ---------------- Kernel 2: attention partial (split-j) ----------------
// 512 thr = 8 waves, lane = query row (64 rows), wave w = j-quad {4w..4w+3}.
// Manual 1-deep software pipeline (A/B register rotation, no copies):
// load chunk i+1 while computing chunk i -> ds_read latency hidden, footprint
// ~95 regs (< the 128-VGPR pin for 512-thr blocks; R6 spill lesson).
__global__ __launch_bounds__(512) void attn_partial(
    const float4* __restrict__ qt4, const float* __restrict__ kk,
    const float* __restrict__ vv, const float* __restrict__ Ksp,
    float4* __restrict__ pacc4, float* __restrict__ ml)
{
    const int it = blockIdx.x;          // 0..15 : 64-row tile (flat rows b*512+n)
    const int js = blockIdx.y;          // 0..15 : 32-key chunk within batch
    const int b  = it >> 3;
    const int irow0 = it * 64;
    const int jrow0 = b * 512 + js * 32;

    __shared__ __attribute__((aligned(16))) float qbuf[64 * QSTR];  // reused for v
    __shared__ __attribute__((aligned(16))) float kbuf[32 * QSTR];
    __shared__ float sL[32][65];
    __shared__ float pl[32][65];

    const int t = threadIdx.x;
    const int w = t >> 6;
    const int l = t & 63;
    const int j0 = w * 4;

    float s[4] = {0.f, 0.f, 0.f, 0.f};

    for (int h = 0; h < 2; ++h) {
        // stage q half-tile 64x128 from qt4[c4][row] (coalesced)
#pragma unroll
        for (int u = 0; u < 4; ++u) {
            int idx = u * 512 + t;
            int c4 = idx >> 6, row = idx & 63;
            *(float4*)&qbuf[row * QSTR + c4 * 4] =
                qt4[(size_t)(h * 32 + c4) * 1024 + irow0 + row];
        }
        // stage k half-tile 32x128
#pragma unroll
        for (int u = 0; u < 2; ++u) {
            int idx = u * 512 + t;
            int row = idx >> 5, c4 = idx & 31;
            *(float4*)&kbuf[row * QSTR + c4 * 4] =
                *(const float4*)&kk[(size_t)(jrow0 + row) * 256 + h * 128 + c4 * 4];
        }
        __syncthreads();

        const float* qrow = &qbuf[l * QSTR];
        const float* k0p = &kbuf[(j0 + 0) * QSTR];
        const float* k1p = &kbuf[(j0 + 1) * QSTR];
        const float* k2p = &kbuf[(j0 + 2) * QSTR];
        const float* k3p = &kbuf[(j0 + 3) * QSTR];

        float4 Aqa,Aqb,Ak0a,Ak0b,Ak1a,Ak1b,Ak2a,Ak2b,Ak3a,Ak3b;
        float4 Bqa,Bqb,Bk0a,Bk0b,Bk1a,Bk1b,Bk2a,Bk2b,Bk3a,Bk3b;

#define LDCH(P, c) \
        P##qa  = *(const float4*)(qrow + (c)); P##qb  = *(const float4*)(qrow + (c) + 4); \
        P##k0a = *(const float4*)(k0p + (c)); P##k0b = *(const float4*)(k0p + (c) + 4); \
        P##k1a = *(const float4*)(k1p + (c)); P##k1b = *(const float4*)(k1p + (c) + 4); \
        P##k2a = *(const float4*)(k2p + (c)); P##k2b = *(const float4*)(k2p + (c) + 4); \
        P##k3a = *(const float4*)(k3p + (c)); P##k3b = *(const float4*)(k3p + (c) + 4);
#define CMPJ(jj, QA, QB, KA, KB) \
        s[jj] += fabsf(QA.x + KA.x); s[jj] += fabsf(QA.y + KA.y); \
        s[jj] += fabsf(QA.z + KA.z); s[jj] += fabsf(QA.w + KA.w); \
        s[jj] += fabsf(QB.x + KB.x); s[jj] += fabsf(QB.y + KB.y); \
        s[jj] += fabsf(QB.z + KB.z); s[jj] += fabsf(QB.w + KB.w);
#define CMPALL(P) \
        CMPJ(0, P##qa, P##qb, P##k0a, P##k0b) CMPJ(1, P##qa, P##qb, P##k1a, P##k1b) \
        CMPJ(2, P##qa, P##qb, P##k2a, P##k2b) CMPJ(3, P##qa, P##qb, P##k3a, P##k3b)

        LDCH(A, 0)
#pragma unroll 1
        for (int c0 = 0; c0 < 128; c0 += 16) {
            LDCH(B, c0 + 8)            // prefetch odd chunk
            CMPALL(A)                  // compute even chunk
            int cn = (c0 + 16) & 127;  // wraps to 0 on last (harmless reload)
            LDCH(A, cn)                // prefetch next even chunk
            CMPALL(B)                  // compute odd chunk
        }
        __syncthreads();   // all score reads done before restage / v-stage
    }

    // score' = 0.5*(Sabs + Ks_j)
    const int jbase = jrow0 + j0;
    float sc[4];
#pragma unroll
    for (int jj = 0; jj < 4; ++jj) {
        float ks = Ksp[jbase + jj] + Ksp[1024 + jbase + jj]
                 + Ksp[2048 + jbase + jj] + Ksp[3072 + jbase + jj];
        sc[jj] = 0.5f * (s[jj] + ks);
        sL[j0 + jj][l] = sc[jj];
    }

    // stage v 32x256 into qbuf (q dead after score)
#pragma unroll
    for (int u = 0; u < 4; ++u) {
        int idx = u * 512 + t;
        int row = idx >> 6, c4 = idx & 63;
        *(float4*)&qbuf[row * VSTR + c4 * 4] =
            *(const float4*)&vv[(size_t)(jrow0 + row) * 256 + c4 * 4];
    }
    __syncthreads();   // publishes sL and v

    float m = -1e30f;
#pragma unroll 8
    for (int j = 0; j < 32; ++j) m = fmaxf(m, sL[j][l]);
#pragma unroll
    for (int jj = 0; jj < 4; ++jj)
        pl[j0 + jj][l] = __expf(sc[jj] - m);
    __syncthreads();

    if (w == 0) {
        float lsum = 0.f;
#pragma unroll 8
        for (int j = 0; j < 32; ++j) lsum += pl[j][l];
        *(float2*)&ml[((size_t)(irow0 + l) * 16 + js) * 2] = make_float2(m, lsum);
    }

    // PV: wave w owns c-slice [32w,32w+32); two acc[16] passes, software-pipelined.
#define PVACC(P, V0, V1, V2, V3) \
        acc[0]  += P * V0.x; acc[1]  += P * V0.y; acc[2]  += P * V0.z; acc[3]  += P * V0.w; \
        acc[4]  += P * V1.x; acc[5]  += P * V1.y; acc[6]  += P * V1.z; acc[7]  += P * V1.w; \
        acc[8]  += P * V2.x; acc[9]  += P * V2.y; acc[10] += P * V2.z; acc[11] += P * V2.w; \
        acc[12] += P * V3.x; acc[13] += P * V3.y; acc[14] += P * V3.z; acc[15] += P * V3.w;
#define LDV(P, jj) \
        P##p0 = pl[jj][l];        P##p1 = pl[(jj) + 1][l]; \
        P##v0 = *(const float4*)(vb + (jj) * VSTR);      P##v1 = *(const float4*)(vb + (jj) * VSTR + 4); \
        P##v2 = *(const float4*)(vb + (jj) * VSTR + 8);  P##v3 = *(const float4*)(vb + (jj) * VSTR + 12); \
        P##w0 = *(const float4*)(vb + ((jj)+1) * VSTR);     P##w1 = *(const float4*)(vb + ((jj)+1) * VSTR + 4); \
        P##w2 = *(const float4*)(vb + ((jj)+1) * VSTR + 8); P##w3 = *(const float4*)(vb + ((jj)+1) * VSTR + 12);

#pragma unroll 1
    for (int pass = 0; pass < 2; ++pass) {
        const int cb = w * 32 + pass * 16;
        const float* vb = &qbuf[cb];
        float acc[16];
#pragma unroll
        for (int i = 0; i < 16; ++i) acc[i] = 0.f;

        float Ap0, Ap1, Bp0, Bp1;
        float4 Av0,Av1,Av2,Av3, Aw0,Aw1,Aw2,Aw3;
        float4 Bv0,Bv1,Bv2,Bv3, Bw0,Bw1,Bw2,Bw3;
        LDV(A, 0)
#pragma unroll 1
        for (int j = 0; j < 32; j += 4) {
            LDV(B, j + 2)
            PVACC(Ap0, Av0, Av1, Av2, Av3)
            PVACC(Ap1, Aw0, Aw1, Aw2, Aw3)
            int jn = (j + 4) & 31;     // wraps to 0 on last (harmless reload)
            LDV(A, jn)
            PVACC(Bp0, Bv0, Bv1, Bv2, Bv3)
            PVACC(Bp1, Bw0, Bw1, Bw2, Bw3)
        }
        // pacc layout: [it][js][c4:64][lane:64] float4 -> b128 coalesced both sides
        float4* pout = pacc4 + (((size_t)it * 16 + js) * 64 + (cb >> 2)) * 64 + l;
        pout[0]   = make_float4(acc[0],  acc[1],  acc[2],  acc[3]);
        pout[64]  = make_float4(acc[4],  acc[5],  acc[6],  acc[7]);
        pout[128] = make_float4(acc[8],  acc[9],  acc[10], acc[11]);
        pout[192] = make_float4(acc[12], acc[13], acc[14], acc[15]);
    }
}

// ---------------- Kernel 3: combine split-j partials -> O^T [256][1024] ----------------
__global__ __launch_bounds__(256) void combine(
    const float4* __restrict__ pacc4, const float* __restrict__ ml, float* __restrict__ OT)
{
    const int it = blockIdx.x;   // 0..15
    const int cs = blockIdx.y;   // 0..15
    const int t  = threadIdx.x;
    const int il = t & 63, cq = t >> 6;      // cq 0..3
    const int row = it * 64 + il;
    const int c4g = cs * 4 + cq;             // 0..63

    float mv[16], lv[16], M = -1e30f;
#pragma unroll
    for (int s = 0; s < 16; ++s) {
        float2 e = *(const float2*)&ml[((size_t)row * 16 + s) * 2];
        mv[s] = e.x; lv[s] = e.y; M = fmaxf(M, e.x);
    }
    float L = 0.f;
    float4 o = make_float4(0.f, 0.f, 0.f, 0.f);
#pragma unroll
    for (int s = 0; s < 16; ++s) {
        float wgt = __expf(mv[s] - M);
        L += wgt * lv[s];
        float4 pv = pacc4[(((size_t)it * 16 + s) * 64 + c4g) * 64 + il];
        o.x += wgt * pv.x; o.y += wgt * pv.y; o.z += wgt * pv.z; o.w += wgt * pv.w;
    }
    float inv = 1.f / L;
    OT[(size_t)(c4g * 4 + 0) * 1024 + row] = o.x * inv;
    OT[(size_t)(c4g * 4 + 1) * 1024 + row] = o.y * inv;
    OT[(size_t)(c4g * 4 + 2) * 1024 + row] = o.z * inv;
    OT[(size_t)(c4g * 4 + 3) * 1024 + row] = o.w * inv;
}

// ---------------- Kernel 4: final projection + bias (LDS double-buffered) ----------------
__global__ __launch_bounds__(256, 2) void gemm_bias(
    const float* __restrict__ OT, const float* __restrict__ W,
    const float* __restrict__ bias, float* __restrict__ out)
{
    const int row0 = blockIdx.x * 32;
    const int d0   = blockIdx.y * 64;

    __shared__ __attribute__((aligned(16))) float AT[2][32][36];
    __shared__ __attribute__((aligned(16))) float WT[2][32][68];

    const int tid = threadIdx.x;
    const int ty = tid >> 4, tx = tid & 15;
    const int acR = tid >> 3, arQ = (tid & 7) * 4;   // A stage: c-row acR, 4 rows arQ
    const int wd = tid >> 2, wc = (tid & 3) * 8;

    const float* ag = OT + (size_t)acR * 1024 + row0 + arQ;
    const float* wg = W + (size_t)(d0 + wd) * 256 + wc;

    float4 ra  = *(const float4*)ag;
    float4 rw0 = *(const float4*)wg;
    float4 rw1 = *(const float4*)(wg + 4);

    *(float4*)&AT[0][acR][arQ] = ra;
    WT[0][wc+0][wd]=rw0.x; WT[0][wc+1][wd]=rw0.y; WT[0][wc+2][wd]=rw0.z; WT[0][wc+3][wd]=rw0.w;
    WT[0][wc+4][wd]=rw1.x; WT[0][wc+5][wd]=rw1.y; WT[0][wc+6][wd]=rw1.z; WT[0][wc+7][wd]=rw1.w;
    __syncthreads();

    float acc[2][4] = {};

#pragma unroll 1
    for (int kc = 0; kc < 8; ++kc) {
        const int cur = kc & 1;
        if (kc < 7) {
            ra  = *(const float4*)(ag + (size_t)(kc + 1) * 32 * 1024);
            rw0 = *(const float4*)(wg + (kc + 1) * 32);
            rw1 = *(const float4*)(wg + (kc + 1) * 32 + 4);
        }
#pragma unroll
        for (int c = 0; c < 32; ++c) {
            float2 a  = *(const float2*)&AT[cur][c][ty * 2];
            float4 w4 = *(const float4*)&WT[cur][c][tx * 4];
            acc[0][0] += a.x * w4.x; acc[0][1] += a.x * w4.y;
            acc[0][2] += a.x * w4.z; acc[0][3] += a.x * w4.w;
            acc[1][0] += a.y * w4.x; acc[1][1] += a.y * w4.y;
            acc[1][2] += a.y * w4.z; acc[1][3] += a.y * w4.w;
        }
        if (kc < 7) {
            const int nx = cur ^ 1;
            *(float4*)&AT[nx][acR][arQ] = ra;
            WT[nx][wc+0][wd]=rw0.x; WT[nx][wc+1][wd]=rw0.y; WT[nx][wc+2][wd]=rw0.z; WT[nx][wc+3][wd]=rw0.w;
            WT[nx][wc+4][wd]=rw1.x; WT[nx][wc+5][wd]=rw1.y; WT[nx][wc+6][wd]=rw1.z; WT[nx][wc+7][wd]=rw1.w;
            __syncthreads();
        }
    }
    float4 bb = *(const float4*)&bias[d0 + tx * 4];
#pragma unroll
    for (int rr = 0; rr < 2; ++rr) {
        float4 o = make_float4(acc[rr][0] + bb.x, acc[rr][1] + bb.y,
                               acc[rr][2] + bb.z, acc[rr][3] + bb.w);
        *(float4*)&out[(size_t)(row0 + ty * 2 + rr) * 256 + d0 + tx * 4] = o;
    }
}

extern "C" void kernel_launch(void* const* d_in, const int* in_sizes, int n_in,
                              void* d_out, int out_size, void* d_ws, size_t ws_size,
                              hipStream_t stream) {
    const float* x  = (const float*)d_in[0];
    const float* Wq = (const float*)d_in[1];
    const float* Wk = (const float*)d_in[2];
    const float* Wv = (const float*)d_in[3];
    const float* Wp = (const float*)d_in[4];
    const float* bp = (const float*)d_in[5];
    float* out = (float*)d_out;
    (void)ws_size; (void)in_sizes; (void)n_in; (void)out_size;

    float* ws = (float*)d_ws;
    const size_t BNC = (size_t)2 * 512 * 256;              // 262144
    float4* qt4 = (float4*)ws;                             // [64 c4][1024] = 1 MB
    float* k    = ws + BNC;
    float* v    = k + BNC;
    float* OT   = v + BNC;                                 // [256][1024]
    float* Ksp  = OT + BNC;                                // [4][1024]
    float4* pacc4 = (float4*)(Ksp + 4 * 1024);             // [16][16][64][64] f4 = 16.8 MB
    float* mlb  = (float*)(pacc4 + (size_t)16 * 16 * 64 * 64);   // [1024][16][2]

    gemm_qkv<<<dim3(32, 4, 3), 256, 0, stream>>>(x, Wq, Wk, Wv, qt4, k, v, Ksp);
    attn_partial<<<dim3(16, 16), 512, 0, stream>>>(qt4, k, v, Ksp, pacc4, mlb);
    combine<<<dim3(16, 16), 256, 0, stream>>>(pacc4, mlb, OT);
    gemm_bias<<<dim3(32, 4), 256, 0, stream>>>(OT, Wp, bp, out);
}